// Round 13
// baseline (118.664 us; speedup 1.0000x reference)
//
#include <hip/hip_runtime.h>

#define FEAT 1024
#define DEPTH 10
#define NLEAF 1024          // 2^DEPTH
#define NODES (NLEAF - 1)   // 1023
#define CAP 320             // per-leaf bucket capacity; mean load 32, sd 5.6
#define TAU 0.03f           // |bf16xbf16 dot| below this -> exact f64 arbiter (~10 sigma)

typedef float f32x4 __attribute__((ext_vector_type(4)));

// ---- f32 full-wave sum via DPP (lane 63 -> broadcast via readlane).
template <int CTRL, int RMASK>
__device__ __forceinline__ float dpp_shift_f(float v) {
    union { float f; int i; } u, r;
    u.f = v;
    r.i = __builtin_amdgcn_update_dpp(0, u.i, CTRL, RMASK, 0xF, true);
    return r.f;
}

__device__ __forceinline__ float wave_sum_f32(float v) {
    v += dpp_shift_f<0x111, 0xF>(v);
    v += dpp_shift_f<0x112, 0xF>(v);
    v += dpp_shift_f<0x114, 0xF>(v);
    v += dpp_shift_f<0x118, 0xF>(v);
    v += dpp_shift_f<0x142, 0xA>(v);
    v += dpp_shift_f<0x143, 0xC>(v);
    union { float f; int i; } u, r;
    u.f = v;
    r.i = __builtin_amdgcn_readlane(u.i, 63);
    return r.f;
}

// ---- f64 versions (escape path only; reproduces R8's verified arbiter).
template <int CTRL, int RMASK>
__device__ __forceinline__ double dpp_shift_d(double v) {
    union { double d; int i[2]; } u, r;
    u.d = v;
    r.i[0] = __builtin_amdgcn_update_dpp(0, u.i[0], CTRL, RMASK, 0xF, true);
    r.i[1] = __builtin_amdgcn_update_dpp(0, u.i[1], CTRL, RMASK, 0xF, true);
    return r.d;
}

__device__ __forceinline__ double wave_sum_f64(double v) {
    v += dpp_shift_d<0x111, 0xF>(v);
    v += dpp_shift_d<0x112, 0xF>(v);
    v += dpp_shift_d<0x114, 0xF>(v);
    v += dpp_shift_d<0x118, 0xF>(v);
    v += dpp_shift_d<0x142, 0xA>(v);
    v += dpp_shift_d<0x143, 0xC>(v);
    union { double d; int i[2]; } u, r;
    u.d = v;
    r.i[0] = __builtin_amdgcn_readlane(u.i[0], 63);
    r.i[1] = __builtin_amdgcn_readlane(u.i[1], 63);
    return r.d;
}

// Exact arbiter: f64 dot of ORIGINAL f32 x-row and f32 X-row (R8-identical
// order). Called only on rare wave-uniform tau escapes; reloads x itself.
__device__ __forceinline__ double dot_f64_escape(
    const float* __restrict__ xp, const float* __restrict__ Xr, int lane)
{
    double p0 = 0.0, p1 = 0.0, p2 = 0.0, p3 = 0.0;
#pragma unroll
    for (int k = 0; k < 4; ++k) {
        f32x4 xl = *reinterpret_cast<const f32x4*>(xp + (lane + 64 * k) * 4);
        f32x4 xc = *reinterpret_cast<const f32x4*>(Xr + (lane + 64 * k) * 4);
        p0 += (double)xl[0] * (double)xc[0];
        p1 += (double)xl[1] * (double)xc[1];
        p2 += (double)xl[2] * (double)xc[2];
        p3 += (double)xl[3] * (double)xc[3];
    }
    return wave_sum_f64((p0 + p1) + (p2 + p3));
}

// bf16-RNE quantize a f32, returned as the bf16 value widened back to f32.
__device__ __forceinline__ float bf16rnd(float f) {
    union { float f; unsigned int u; } v;
    v.f = f;
    unsigned int u = v.u + (0x7FFFu + ((v.u >> 16) & 1u));
    v.u = u & 0xFFFF0000u;
    return v.f;
}

// ---------------- prep: X f32 -> permuted bf16 (RNE); also zero cursors. ----------------
// Out layout per row: element (lane*16 + j) = in element ((lane + 64*(j>>2))*4 + (j&3)).
__global__ __launch_bounds__(256) void prep_kernel(
    const float* __restrict__ Xw,
    unsigned short* __restrict__ Xb,
    int* __restrict__ cursor)
{
    const int gid = blockIdx.x * 256 + threadIdx.x;       // 0 .. NODES*FEAT-1
    const int r = gid >> 10;
    const int o = gid & 1023;
    const int lane = o >> 4, j = o & 15;
    const int src = ((lane + 64 * (j >> 2)) << 2) + (j & 3);

    union { float f; unsigned int u; } v;
    v.f = Xw[(size_t)r * FEAT + src];
    unsigned int u = v.u;
    u += 0x7FFFu + ((u >> 16) & 1u);                      // round-to-nearest-even
    Xb[(size_t)r * FEAT + o] = (unsigned short)(u >> 16);

    if (gid < NLEAF) cursor[gid] = 0;
}

// ---------------- Pass 1: path. 1 sample/wave, child-prefetch pipeline. ----------------
// Level d: row of node n_d already in regs (r0,r1). Issue BOTH child-row loads
// immediately (addresses need no compute), dot the resident row, reduce, sign,
// then cndmask-select the arrived child regs. The L2 load latency is hidden
// under dot+reduce instead of sitting on the sign->dot critical path.
__global__ __launch_bounds__(256) void path_kernel(
    const float* __restrict__ x,
    const float* __restrict__ Xw,
    const unsigned short* __restrict__ Xb,
    float* __restrict__ lam_out,
    int* __restrict__ order,
    int* __restrict__ cursor,
    int nsamples)
{
    const int wave = threadIdx.x >> 6;
    const int lane = threadIdx.x & 63;
    const int s = blockIdx.x * 4 + wave;
    if (s >= nsamples) return;

    const float* xp = x + (size_t)s * FEAT;

    // x fragment, pre-rounded to bf16 (kept as f32 values): dot is bf16xbf16
    // with f32-fma accumulate. Original f32 x is reloaded only on escapes.
    f32x4 xvb[4];
#pragma unroll
    for (int k = 0; k < 4; ++k) {
        f32x4 t = __builtin_nontemporal_load(
            reinterpret_cast<const f32x4*>(xp + (lane + 64 * k) * 4));
        xvb[k][0] = bf16rnd(t[0]);
        xvb[k][1] = bf16rnd(t[1]);
        xvb[k][2] = bf16rnd(t[2]);
        xvb[k][3] = bf16rnd(t[3]);
    }

    // prologue: row 0 resident
    uint4 r0, r1;
    {
        const uint4* br = reinterpret_cast<const uint4*>(Xb + (size_t)lane * 16);
        r0 = br[0];
        r1 = br[1];
    }

    int cur = 0;
#pragma unroll
    for (int d = 0; d < DEPTH; ++d) {
        // (1) issue both child-row loads NOW (no dependence on this level's dot)
        uint4 cl0, cl1, cr0, cr1;
        if (d < DEPTH - 1) {
            const uint4* bl = reinterpret_cast<const uint4*>(
                Xb + (size_t)(2 * cur + 1) * FEAT + lane * 16);
            const uint4* br = reinterpret_cast<const uint4*>(
                Xb + (size_t)(2 * cur + 2) * FEAT + lane * 16);
            cl0 = bl[0]; cl1 = bl[1];
            cr0 = br[0]; cr1 = br[1];
        }

        // (2) dot with resident row
        const unsigned int u8[8] = {r0.x, r0.y, r0.z, r0.w, r1.x, r1.y, r1.z, r1.w};
        float a0 = 0.f, a1 = 0.f, a2 = 0.f, a3 = 0.f;
#pragma unroll
        for (int k = 0; k < 4; ++k) {
            union { unsigned int u; float f; } c0, c1, c2, c3;
            c0.u = u8[2 * k] << 16;
            c1.u = u8[2 * k] & 0xFFFF0000u;
            c2.u = u8[2 * k + 1] << 16;
            c3.u = u8[2 * k + 1] & 0xFFFF0000u;
            a0 = fmaf(xvb[k][0], c0.f, a0);
            a1 = fmaf(xvb[k][1], c1.f, a1);
            a2 = fmaf(xvb[k][2], c2.f, a2);
            a3 = fmaf(xvb[k][3], c3.f, a3);
        }
        const float p32 = wave_sum_f32((a0 + a1) + (a2 + a3));

        // (3) tau escape: rare, wave-uniform, R8-exact f64 arbiter.
        double p;
        if (__builtin_expect(__builtin_fabsf(p32) < TAU, 0))
            p = dot_f64_escape(xp, Xw + (size_t)cur * FEAT, lane);
        else
            p = (double)p32;

        if (lane == 0) lam_out[(size_t)s * DEPTH + d] = (float)p;
        const bool right = (p > 0.0);
        cur = 2 * cur + 1 + (right ? 1 : 0);

        // (4) keep both child loads alive (block select-of-loads refold), then
        //     register-select the taken child as the next resident row.
        if (d < DEPTH - 1) {
            asm volatile("" ::
                "v"(cl0.x), "v"(cl0.y), "v"(cl0.z), "v"(cl0.w),
                "v"(cl1.x), "v"(cl1.y), "v"(cl1.z), "v"(cl1.w),
                "v"(cr0.x), "v"(cr0.y), "v"(cr0.z), "v"(cr0.w),
                "v"(cr1.x), "v"(cr1.y), "v"(cr1.z), "v"(cr1.w));
            r0 = right ? cr0 : cl0;
            r1 = right ? cr1 : cl1;
        }
    }

    if (lane == 0) {
        const int b = cur - NODES;
        const int pos = atomicAdd(&cursor[b], 1);
        if (pos < CAP) order[b * CAP + pos] = s;
    }
}

// ---------------- Pass 2: emit. TWO 512-thread blocks per leaf. ----------------
__global__ __launch_bounds__(512) void emit_kernel(
    const float* __restrict__ Yw,
    const float* __restrict__ lam,
    const int* __restrict__ order,
    const int* __restrict__ cursor,
    float* __restrict__ out)
{
    __shared__ float ylds[DEPTH][FEAT];
    const int b = blockIdx.x >> 1;
    const int half = blockIdx.x & 1;
    const int leafPlus = b + NLEAF;              // (final cur) + 1

    for (int i = threadIdx.x; i < DEPTH * (FEAT / 4); i += 512) {
        const int d = i >> 8;                    // FEAT/4 = 256 chunks per row
        const int c = i & 255;
        const int node = (leafPlus >> (DEPTH - d)) - 1;
        reinterpret_cast<f32x4*>(ylds[d])[c] =
            reinterpret_cast<const f32x4*>(Yw + (size_t)node * FEAT)[c];
    }
    __syncthreads();

    int cnt = cursor[b];
    if (cnt > CAP) cnt = CAP;
    const int wave = threadIdx.x >> 6;
    const int lane = threadIdx.x & 63;

    for (int i = half * 8 + wave; i < cnt; i += 16) {
        const int s = __builtin_amdgcn_readfirstlane(order[b * CAP + i]);

        const float* lp = lam + (size_t)s * DEPTH;
        float lm[DEPTH];
#pragma unroll
        for (int d = 0; d < DEPTH; ++d)
            lm[d] = lp[d];                       // wave-uniform -> s_load

        float* op = out + (size_t)s * FEAT;
#pragma unroll
        for (int k = 0; k < 4; ++k) {
            f32x4 o = (f32x4)(0.f);
#pragma unroll
            for (int d = 0; d < DEPTH; ++d)
                o += lm[d] * reinterpret_cast<const f32x4*>(ylds[d])[lane + 64 * k];
            __builtin_nontemporal_store(o, reinterpret_cast<f32x4*>(op + 4 * (lane + 64 * k)));
        }
    }
}

// ---------------- Fallback (R1 single kernel) if ws too small ----------------
__global__ __launch_bounds__(256) void fff_fallback(
    const float* __restrict__ x, const float* __restrict__ Xw,
    const float* __restrict__ Yw, float* __restrict__ out, int nsamples)
{
    const int wave = threadIdx.x >> 6, lane = threadIdx.x & 63;
    const int s = blockIdx.x * 4 + wave;
    if (s >= nsamples) return;
    const float* xp = x + (size_t)s * FEAT;
    f32x4 xv[4], acc[4];
#pragma unroll
    for (int k = 0; k < 4; ++k) {
        xv[k] = *reinterpret_cast<const f32x4*>(xp + (lane + 64 * k) * 4);
        acc[k] = (f32x4)(0.f);
    }
    int cur = 0;
#pragma unroll
    for (int d = 0; d < DEPTH; ++d) {
        const float* Xr = Xw + (size_t)cur * FEAT;
        double p = 0.0;
#pragma unroll
        for (int k = 0; k < 4; ++k) {
            f32x4 xc = *reinterpret_cast<const f32x4*>(Xr + (lane + 64 * k) * 4);
            p += (double)xv[k][0] * (double)xc[0];
            p += (double)xv[k][1] * (double)xc[1];
            p += (double)xv[k][2] * (double)xc[2];
            p += (double)xv[k][3] * (double)xc[3];
        }
#pragma unroll
        for (int off = 32; off >= 1; off >>= 1) p += __shfl_xor(p, off, 64);
        const float lamv = (float)p;
        const float* Yr = Yw + (size_t)cur * FEAT;
#pragma unroll
        for (int k = 0; k < 4; ++k) {
            f32x4 yc = *reinterpret_cast<const f32x4*>(Yr + (lane + 64 * k) * 4);
            acc[k] += lamv * yc;
        }
        cur = 2 * cur + 1 + (p > 0.0 ? 1 : 0);
    }
    float* op = out + (size_t)s * FEAT;
#pragma unroll
    for (int k = 0; k < 4; ++k)
        *reinterpret_cast<f32x4*>(op + 4 * (lane + 64 * k)) = acc[k];
}

extern "C" void kernel_launch(void* const* d_in, const int* in_sizes, int n_in,
                              void* d_out, int out_size, void* d_ws, size_t ws_size,
                              hipStream_t stream) {
    const float* oldx = (const float*)d_in[0];
    const float* Xw   = (const float*)d_in[1];
    const float* Yw   = (const float*)d_in[2];
    float* out = (float*)d_out;

    const int ns = in_sizes[0] / FEAT;           // 32768

    const size_t XbB   = (size_t)NODES * FEAT * sizeof(unsigned short); // 2 MB
    const size_t lamB  = (size_t)ns * DEPTH * sizeof(float);
    const size_t ordB  = (size_t)NLEAF * CAP * sizeof(int);
    const size_t curB  = NLEAF * sizeof(int);
    const size_t need  = XbB + lamB + ordB + curB;

    if (ws_size < need) {
        fff_fallback<<<(ns + 3) / 4, 256, 0, stream>>>(oldx, Xw, Yw, out, ns);
        return;
    }

    char* w = (char*)d_ws;
    unsigned short* Xb = (unsigned short*)w;  w += XbB;
    float* lam    = (float*)w;  w += lamB;
    int*   order  = (int*)w;    w += ordB;
    int*   cursor = (int*)w;

    // prep: bf16-permute X + zero cursors (NODES*FEAT threads exactly)
    prep_kernel<<<(NODES * FEAT) / 256, 256, 0, stream>>>(Xw, Xb, cursor);
    // 1 sample/wave, 4 waves/block
    path_kernel<<<(ns + 3) / 4, 256, 0, stream>>>(oldx, Xw, Xb, lam, order, cursor, ns);
    emit_kernel<<<2 * NLEAF, 512, 0, stream>>>(Yw, lam, order, cursor, out);
}

// Round 14
// 103.841 us; speedup vs baseline: 1.1427x; 1.1427x over previous
//
#include <hip/hip_runtime.h>

#define FEAT 1024
#define DEPTH 10
#define NLEAF 1024          // 2^DEPTH
#define NODES (NLEAF - 1)   // 1023
#define CAP 320             // per-leaf bucket capacity; mean load 32, sd 5.6
#define TAU 0.02f           // |bf16 dot| below this -> exact f64 arbiter (~13 sigma)

#define HAS_DOT2 __has_builtin(__builtin_amdgcn_fdot2_f32_bf16)

typedef float f32x4 __attribute__((ext_vector_type(4)));
typedef short s16x2 __attribute__((ext_vector_type(2)));

// ---- f32 full-wave sum via DPP (lane 63 -> broadcast via readlane).
template <int CTRL, int RMASK>
__device__ __forceinline__ float dpp_shift_f(float v) {
    union { float f; int i; } u, r;
    u.f = v;
    r.i = __builtin_amdgcn_update_dpp(0, u.i, CTRL, RMASK, 0xF, true);
    return r.f;
}

__device__ __forceinline__ float wave_sum_f32(float v) {
    v += dpp_shift_f<0x111, 0xF>(v);
    v += dpp_shift_f<0x112, 0xF>(v);
    v += dpp_shift_f<0x114, 0xF>(v);
    v += dpp_shift_f<0x118, 0xF>(v);
    v += dpp_shift_f<0x142, 0xA>(v);
    v += dpp_shift_f<0x143, 0xC>(v);
    union { float f; int i; } u, r;
    u.f = v;
    r.i = __builtin_amdgcn_readlane(u.i, 63);
    return r.f;
}

// ---- f64 versions (escape path only; reproduces R8's verified arbiter).
template <int CTRL, int RMASK>
__device__ __forceinline__ double dpp_shift_d(double v) {
    union { double d; int i[2]; } u, r;
    u.d = v;
    r.i[0] = __builtin_amdgcn_update_dpp(0, u.i[0], CTRL, RMASK, 0xF, true);
    r.i[1] = __builtin_amdgcn_update_dpp(0, u.i[1], CTRL, RMASK, 0xF, true);
    return r.d;
}

__device__ __forceinline__ double wave_sum_f64(double v) {
    v += dpp_shift_d<0x111, 0xF>(v);
    v += dpp_shift_d<0x112, 0xF>(v);
    v += dpp_shift_d<0x114, 0xF>(v);
    v += dpp_shift_d<0x118, 0xF>(v);
    v += dpp_shift_d<0x142, 0xA>(v);
    v += dpp_shift_d<0x143, 0xC>(v);
    union { double d; int i[2]; } u, r;
    u.d = v;
    r.i[0] = __builtin_amdgcn_readlane(u.i[0], 63);
    r.i[1] = __builtin_amdgcn_readlane(u.i[1], 63);
    return r.d;
}

// Exact arbiter: f64 dot of ORIGINAL f32 x-row and f32 X-row (R8-identical
// order). Called only on rare wave-uniform tau escapes; reloads x itself.
__device__ __forceinline__ double dot_f64_escape(
    const float* __restrict__ xp, const float* __restrict__ Xr, int lane)
{
    double p0 = 0.0, p1 = 0.0, p2 = 0.0, p3 = 0.0;
#pragma unroll
    for (int k = 0; k < 4; ++k) {
        f32x4 xl = *reinterpret_cast<const f32x4*>(xp + (lane + 64 * k) * 4);
        f32x4 xc = *reinterpret_cast<const f32x4*>(Xr + (lane + 64 * k) * 4);
        p0 += (double)xl[0] * (double)xc[0];
        p1 += (double)xl[1] * (double)xc[1];
        p2 += (double)xl[2] * (double)xc[2];
        p3 += (double)xl[3] * (double)xc[3];
    }
    return wave_sum_f64((p0 + p1) + (p2 + p3));
}

// bf16-RNE: two f32 -> packed 2xbf16 in a uint (lo = first elem).
__device__ __forceinline__ unsigned int pack_bf16x2(float lo, float hi) {
    union { float f; unsigned int u; } a, b;
    a.f = lo; b.f = hi;
    const unsigned int ua = (a.u + (0x7FFFu + ((a.u >> 16) & 1u))) >> 16;
    const unsigned int ub = (b.u + (0x7FFFu + ((b.u >> 16) & 1u))) >> 16;
    return (ua & 0xFFFFu) | (ub << 16);
}

#if HAS_DOT2
__device__ __forceinline__ float fdot2bf(unsigned int a, unsigned int b, float c) {
    union { unsigned int u; s16x2 v; } ua, ub;
    ua.u = a; ub.u = b;
    return __builtin_amdgcn_fdot2_f32_bf16(ua.v, ub.v, c, false);
}
#endif

// ---------------- prep: X f32 -> permuted bf16 (RNE); also zero cursors. ----------------
// Out layout per row: element (lane*16 + j) = in element ((lane + 64*(j>>2))*4 + (j&3)).
__global__ __launch_bounds__(256) void prep_kernel(
    const float* __restrict__ Xw,
    unsigned short* __restrict__ Xb,
    int* __restrict__ cursor)
{
    const int gid = blockIdx.x * 256 + threadIdx.x;       // 0 .. NODES*FEAT-1
    const int r = gid >> 10;
    const int o = gid & 1023;
    const int lane = o >> 4, j = o & 15;
    const int src = ((lane + 64 * (j >> 2)) << 2) + (j & 3);

    union { float f; unsigned int u; } v;
    v.f = Xw[(size_t)r * FEAT + src];
    unsigned int u = v.u;
    u += 0x7FFFu + ((u >> 16) & 1u);                      // round-to-nearest-even
    Xb[(size_t)r * FEAT + o] = (unsigned short)(u >> 16);

    if (gid < NLEAF) cursor[gid] = 0;
}

// ---------------- Pass 1: path. 2 samples/wave, single-child loads. ----------------
// Residency experiment: launch_bounds pins VGPR so 8 waves/SIMD can reside;
// packed-bf16 x + v_dot2_f32_bf16 shrink both registers and per-level issue.
#if HAS_DOT2
__global__ __launch_bounds__(256, 8) void path_kernel(
#else
__global__ __launch_bounds__(256, 6) void path_kernel(
#endif
    const float* __restrict__ x,
    const float* __restrict__ Xw,
    const unsigned short* __restrict__ Xb,
    float* __restrict__ lam_out,
    int* __restrict__ order,
    int* __restrict__ cursor,
    int nsamples)
{
    const int wave = threadIdx.x >> 6;
    const int lane = threadIdx.x & 63;
    const int sA = (blockIdx.x * 4 + wave) * 2;
    const int sB = sA + 1;
    if (sA >= nsamples) return;

    const float* xpA = x + (size_t)sA * FEAT;
    const float* xpB = x + (size_t)sB * FEAT;

#if HAS_DOT2
    // x pre-rounded to bf16 and PACKED: 8 uints per sample (16 VGPR total).
    unsigned int xkA[8], xkB[8];
#pragma unroll
    for (int k = 0; k < 4; ++k) {
        f32x4 tA = __builtin_nontemporal_load(
            reinterpret_cast<const f32x4*>(xpA + (lane + 64 * k) * 4));
        f32x4 tB = __builtin_nontemporal_load(
            reinterpret_cast<const f32x4*>(xpB + (lane + 64 * k) * 4));
        xkA[2 * k]     = pack_bf16x2(tA[0], tA[1]);
        xkA[2 * k + 1] = pack_bf16x2(tA[2], tA[3]);
        xkB[2 * k]     = pack_bf16x2(tB[0], tB[1]);
        xkB[2 * k + 1] = pack_bf16x2(tB[2], tB[3]);
    }
#else
    f32x4 xvA[4], xvB[4];
#pragma unroll
    for (int k = 0; k < 4; ++k) {
        xvA[k] = __builtin_nontemporal_load(
            reinterpret_cast<const f32x4*>(xpA + (lane + 64 * k) * 4));
        xvB[k] = __builtin_nontemporal_load(
            reinterpret_cast<const f32x4*>(xpB + (lane + 64 * k) * 4));
    }
#endif

    int curA = 0, curB = 0;
#pragma unroll
    for (int d = 0; d < DEPTH; ++d) {
        const uint4* brA = reinterpret_cast<const uint4*>(
            Xb + (size_t)curA * FEAT + lane * 16);
        const uint4* brB = reinterpret_cast<const uint4*>(
            Xb + (size_t)curB * FEAT + lane * 16);
        const uint4 qA0 = brA[0], qA1 = brA[1];
        const uint4 qB0 = brB[0], qB1 = brB[1];
        const unsigned int uA[8] = {qA0.x, qA0.y, qA0.z, qA0.w,
                                    qA1.x, qA1.y, qA1.z, qA1.w};
        const unsigned int uB[8] = {qB0.x, qB0.y, qB0.z, qB0.w,
                                    qB1.x, qB1.y, qB1.z, qB1.w};

        float a0 = 0.f, a1 = 0.f, a2 = 0.f, a3 = 0.f;
        float b0 = 0.f, b1 = 0.f, b2 = 0.f, b3 = 0.f;
#if HAS_DOT2
        // 8 dot2 per sample, 4 independent acc chains (depth 2).
        a0 = fdot2bf(xkA[0], uA[0], a0);  a1 = fdot2bf(xkA[1], uA[1], a1);
        a2 = fdot2bf(xkA[2], uA[2], a2);  a3 = fdot2bf(xkA[3], uA[3], a3);
        a0 = fdot2bf(xkA[4], uA[4], a0);  a1 = fdot2bf(xkA[5], uA[5], a1);
        a2 = fdot2bf(xkA[6], uA[6], a2);  a3 = fdot2bf(xkA[7], uA[7], a3);
        b0 = fdot2bf(xkB[0], uB[0], b0);  b1 = fdot2bf(xkB[1], uB[1], b1);
        b2 = fdot2bf(xkB[2], uB[2], b2);  b3 = fdot2bf(xkB[3], uB[3], b3);
        b0 = fdot2bf(xkB[4], uB[4], b0);  b1 = fdot2bf(xkB[5], uB[5], b1);
        b2 = fdot2bf(xkB[6], uB[6], b2);  b3 = fdot2bf(xkB[7], uB[7], b3);
#else
#pragma unroll
        for (int k = 0; k < 4; ++k) {
            union { unsigned int u; float f; } c0, c1, c2, c3, e0, e1, e2, e3;
            c0.u = uA[2 * k] << 16;
            c1.u = uA[2 * k] & 0xFFFF0000u;
            c2.u = uA[2 * k + 1] << 16;
            c3.u = uA[2 * k + 1] & 0xFFFF0000u;
            a0 = fmaf(xvA[k][0], c0.f, a0);
            a1 = fmaf(xvA[k][1], c1.f, a1);
            a2 = fmaf(xvA[k][2], c2.f, a2);
            a3 = fmaf(xvA[k][3], c3.f, a3);
            e0.u = uB[2 * k] << 16;
            e1.u = uB[2 * k] & 0xFFFF0000u;
            e2.u = uB[2 * k + 1] << 16;
            e3.u = uB[2 * k + 1] & 0xFFFF0000u;
            b0 = fmaf(xvB[k][0], e0.f, b0);
            b1 = fmaf(xvB[k][1], e1.f, b1);
            b2 = fmaf(xvB[k][2], e2.f, b2);
            b3 = fmaf(xvB[k][3], e3.f, b3);
        }
#endif
        const float pA32 = wave_sum_f32((a0 + a1) + (a2 + a3));
        const float pB32 = wave_sum_f32((b0 + b1) + (b2 + b3));

        // tau escape: rare, wave-uniform, R8-exact f64 arbiter from memory.
        double pA, pB;
        if (__builtin_expect(__builtin_fabsf(pA32) < TAU, 0))
            pA = dot_f64_escape(xpA, Xw + (size_t)curA * FEAT, lane);
        else
            pA = (double)pA32;
        if (__builtin_expect(__builtin_fabsf(pB32) < TAU, 0))
            pB = dot_f64_escape(xpB, Xw + (size_t)curB * FEAT, lane);
        else
            pB = (double)pB32;

        if (lane == 0) {
            lam_out[(size_t)sA * DEPTH + d] = (float)pA;
            lam_out[(size_t)sB * DEPTH + d] = (float)pB;
        }
        curA = 2 * curA + 1 + (pA > 0.0 ? 1 : 0);
        curB = 2 * curB + 1 + (pB > 0.0 ? 1 : 0);
    }

    if (lane == 0) {
        const int bA = curA - NODES;
        const int bB = curB - NODES;
        const int pA_ = atomicAdd(&cursor[bA], 1);
        const int pB_ = atomicAdd(&cursor[bB], 1);
        if (pA_ < CAP) order[bA * CAP + pA_] = sA;
        if (pB_ < CAP) order[bB * CAP + pB_] = sB;
    }
}

// ---------------- Pass 2: emit. TWO 512-thread blocks per leaf. ----------------
__global__ __launch_bounds__(512) void emit_kernel(
    const float* __restrict__ Yw,
    const float* __restrict__ lam,
    const int* __restrict__ order,
    const int* __restrict__ cursor,
    float* __restrict__ out)
{
    __shared__ float ylds[DEPTH][FEAT];
    const int b = blockIdx.x >> 1;
    const int half = blockIdx.x & 1;
    const int leafPlus = b + NLEAF;              // (final cur) + 1

    for (int i = threadIdx.x; i < DEPTH * (FEAT / 4); i += 512) {
        const int d = i >> 8;                    // FEAT/4 = 256 chunks per row
        const int c = i & 255;
        const int node = (leafPlus >> (DEPTH - d)) - 1;
        reinterpret_cast<f32x4*>(ylds[d])[c] =
            reinterpret_cast<const f32x4*>(Yw + (size_t)node * FEAT)[c];
    }
    __syncthreads();

    int cnt = cursor[b];
    if (cnt > CAP) cnt = CAP;
    const int wave = threadIdx.x >> 6;
    const int lane = threadIdx.x & 63;

    for (int i = half * 8 + wave; i < cnt; i += 16) {
        const int s = __builtin_amdgcn_readfirstlane(order[b * CAP + i]);

        const float* lp = lam + (size_t)s * DEPTH;
        float lm[DEPTH];
#pragma unroll
        for (int d = 0; d < DEPTH; ++d)
            lm[d] = lp[d];                       // wave-uniform -> s_load

        float* op = out + (size_t)s * FEAT;
#pragma unroll
        for (int k = 0; k < 4; ++k) {
            f32x4 o = (f32x4)(0.f);
#pragma unroll
            for (int d = 0; d < DEPTH; ++d)
                o += lm[d] * reinterpret_cast<const f32x4*>(ylds[d])[lane + 64 * k];
            __builtin_nontemporal_store(o, reinterpret_cast<f32x4*>(op + 4 * (lane + 64 * k)));
        }
    }
}

// ---------------- Fallback (R1 single kernel) if ws too small ----------------
__global__ __launch_bounds__(256) void fff_fallback(
    const float* __restrict__ x, const float* __restrict__ Xw,
    const float* __restrict__ Yw, float* __restrict__ out, int nsamples)
{
    const int wave = threadIdx.x >> 6, lane = threadIdx.x & 63;
    const int s = blockIdx.x * 4 + wave;
    if (s >= nsamples) return;
    const float* xp = x + (size_t)s * FEAT;
    f32x4 xv[4], acc[4];
#pragma unroll
    for (int k = 0; k < 4; ++k) {
        xv[k] = *reinterpret_cast<const f32x4*>(xp + (lane + 64 * k) * 4);
        acc[k] = (f32x4)(0.f);
    }
    int cur = 0;
#pragma unroll
    for (int d = 0; d < DEPTH; ++d) {
        const float* Xr = Xw + (size_t)cur * FEAT;
        double p = 0.0;
#pragma unroll
        for (int k = 0; k < 4; ++k) {
            f32x4 xc = *reinterpret_cast<const f32x4*>(Xr + (lane + 64 * k) * 4);
            p += (double)xv[k][0] * (double)xc[0];
            p += (double)xv[k][1] * (double)xc[1];
            p += (double)xv[k][2] * (double)xc[2];
            p += (double)xv[k][3] * (double)xc[3];
        }
#pragma unroll
        for (int off = 32; off >= 1; off >>= 1) p += __shfl_xor(p, off, 64);
        const float lamv = (float)p;
        const float* Yr = Yw + (size_t)cur * FEAT;
#pragma unroll
        for (int k = 0; k < 4; ++k) {
            f32x4 yc = *reinterpret_cast<const f32x4*>(Yr + (lane + 64 * k) * 4);
            acc[k] += lamv * yc;
        }
        cur = 2 * cur + 1 + (p > 0.0 ? 1 : 0);
    }
    float* op = out + (size_t)s * FEAT;
#pragma unroll
    for (int k = 0; k < 4; ++k)
        *reinterpret_cast<f32x4*>(op + 4 * (lane + 64 * k)) = acc[k];
}

extern "C" void kernel_launch(void* const* d_in, const int* in_sizes, int n_in,
                              void* d_out, int out_size, void* d_ws, size_t ws_size,
                              hipStream_t stream) {
    const float* oldx = (const float*)d_in[0];
    const float* Xw   = (const float*)d_in[1];
    const float* Yw   = (const float*)d_in[2];
    float* out = (float*)d_out;

    const int ns = in_sizes[0] / FEAT;           // 32768

    const size_t XbB   = (size_t)NODES * FEAT * sizeof(unsigned short); // 2 MB
    const size_t lamB  = (size_t)ns * DEPTH * sizeof(float);
    const size_t ordB  = (size_t)NLEAF * CAP * sizeof(int);
    const size_t curB  = NLEAF * sizeof(int);
    const size_t need  = XbB + lamB + ordB + curB;

    if (ws_size < need) {
        fff_fallback<<<(ns + 3) / 4, 256, 0, stream>>>(oldx, Xw, Yw, out, ns);
        return;
    }

    char* w = (char*)d_ws;
    unsigned short* Xb = (unsigned short*)w;  w += XbB;
    float* lam    = (float*)w;  w += lamB;
    int*   order  = (int*)w;    w += ordB;
    int*   cursor = (int*)w;

    // prep: bf16-permute X + zero cursors (NODES*FEAT threads exactly)
    prep_kernel<<<(NODES * FEAT) / 256, 256, 0, stream>>>(Xw, Xb, cursor);
    // 2 samples/wave, 4 waves/block
    path_kernel<<<(ns + 7) / 8, 256, 0, stream>>>(oldx, Xw, Xb, lam, order, cursor, ns);
    emit_kernel<<<2 * NLEAF, 512, 0, stream>>>(Yw, lam, order, cursor, out);
}